// Round 1
// baseline (690.526 us; speedup 1.0000x reference)
//
#include <hip/hip_runtime.h>

#define B_ 8
#define C_ 256
#define H_ 128
#define W_ 128
#define NW_ 512
#define HW_ (H_*W_)
#define EPS_ 1e-5f

// Tile: 4 rows x 16 cols = 64 pixels per block, all 256 output channels.
#define TH_ 4
#define TW_ 16

// ---------------- Kernel 1: BN batch stats -> scale/shift ----------------
__global__ __launch_bounds__(1024)
void bn_stats(const float* __restrict__ x, const float* __restrict__ gamma,
              const float* __restrict__ beta, float* __restrict__ sc_sh) {
  const int c = blockIdx.x;
  const int tid = threadIdx.x;
  float s = 0.f, s2 = 0.f;
  for (int b = 0; b < B_; ++b) {
    const float4* p = (const float4*)(x + ((size_t)((size_t)b*C_ + c)) * HW_);
    #pragma unroll
    for (int i = 0; i < (HW_/4)/1024; ++i) {
      float4 v = p[tid + i*1024];
      s  += v.x + v.y + v.z + v.w;
      s2 += v.x*v.x + v.y*v.y + v.z*v.z + v.w*v.w;
    }
  }
  __shared__ float rs[1024];
  __shared__ float rq[1024];
  rs[tid] = s; rq[tid] = s2;
  __syncthreads();
  for (int off = 512; off > 0; off >>= 1) {
    if (tid < off) { rs[tid] += rs[tid+off]; rq[tid] += rq[tid+off]; }
    __syncthreads();
  }
  if (tid == 0) {
    const float n = (float)(B_*HW_);
    float mean = rs[0] / n;
    float var  = rq[0] / n - mean*mean;      // biased var (jnp.var)
    float scl  = gamma[c] * rsqrtf(var + EPS_);
    sc_sh[c]      = scl;
    sc_sh[C_ + c] = beta[c] - mean*scl;
  }
}

// ---------------- Kernel 2: fused dwconv + relu + 1x1 + residual ----------------
// grid: (W_/TW_, H_/TH_, B_), block: 256 threads
__global__ __launch_bounds__(256, 3)
void fused_main(const float* __restrict__ x, const float* __restrict__ lbpw,
                const float* __restrict__ w1, const float* __restrict__ b1,
                const float* __restrict__ sc_sh, float* __restrict__ out) {
  const int tid = threadIdx.x;
  const int b   = blockIdx.z;
  const int h0  = blockIdx.y * TH_;
  const int w0  = blockIdx.x * TW_;

  __shared__ __align__(16) float s_scale[C_];
  __shared__ __align__(16) float s_shift[C_];
  __shared__ __align__(16) float s_xn[16][TH_+2][TW_+2];  // 16ch x 6 x 18, normalized, zero halo
  __shared__ __align__(16) float s_y[32][68];             // 32 y-ch x 64 px (pad->68: bank spread, 16B rows)
  __shared__ __align__(16) float s_w1[32][260];           // w1t chunk [o][c] (pad->260: 16B rows)

  s_scale[tid] = sc_sh[tid];
  s_shift[tid] = sc_sh[C_ + tid];

  const int ci = tid >> 3;        // 0..31 -> output channels ci*8..ci*8+7
  const int pi = tid & 7;         // 0..7  -> pixels pi*8..pi*8+7

  float acc[8][8];
  #pragma unroll
  for (int i = 0; i < 8; ++i)
    #pragma unroll
    for (int j = 0; j < 8; ++j) acc[i][j] = 0.f;

  __syncthreads();

  for (int kc = 0; kc < 16; ++kc) {
    const int c0 = kc * 16;       // input-channel base of this chunk
    const int o0 = kc * 32;       // y-channel base of this chunk

    // --- stage normalized input tile (zero padding in xn space) ---
    for (int idx = tid; idx < 16*(TH_+2)*(TW_+2); idx += 256) {
      int cl  = idx / ((TH_+2)*(TW_+2));
      int rem = idx - cl * ((TH_+2)*(TW_+2));
      int r   = rem / (TW_+2);
      int col = rem - r * (TW_+2);
      int h = h0 + r - 1;
      int w = w0 + col - 1;
      float v = 0.f;
      if (h >= 0 && h < H_ && w >= 0 && w < W_) {
        float xv = x[(((b*C_ + c0 + cl)*H_ + h)*W_) + w];
        v = fmaf(xv, s_scale[c0 + cl], s_shift[c0 + cl]);
      }
      s_xn[cl][r][col] = v;
    }

    // --- stage w1 chunk transposed: s_w1[oo][c] = w1[c][o0+oo] ---
    {
      const int o4 = (tid & 7) * 4;     // 0,4,...,28
      const int cb = tid >> 3;          // 0..31
      #pragma unroll
      for (int j = 0; j < 8; ++j) {
        const int c = cb + j*32;
        const float4 v = *(const float4*)&w1[(size_t)c*NW_ + o0 + o4];
        s_w1[o4+0][c] = v.x;
        s_w1[o4+1][c] = v.y;
        s_w1[o4+2][c] = v.z;
        s_w1[o4+3][c] = v.w;
      }
    }
    __syncthreads();

    // --- depthwise 3x3 conv + relu -> s_y[o_local][p] ---
    {
      const int ol   = tid >> 3;         // 0..31
      const int cin  = ol >> 1;          // chunk-local input channel
      const int pr   = pi >> 1;          // tile row 0..3
      const int pc0  = (pi & 1) * 8;     // tile col start 0 or 8
      const float* wp = lbpw + (size_t)(o0 + ol) * 9;
      float y[8];
      #pragma unroll
      for (int j = 0; j < 8; ++j) y[j] = 0.f;
      #pragma unroll
      for (int di = 0; di < 3; ++di) {
        float row[10];
        #pragma unroll
        for (int k = 0; k < 10; ++k) row[k] = s_xn[cin][pr+di][pc0+k];
        #pragma unroll
        for (int dj = 0; dj < 3; ++dj) {
          const float wv = wp[di*3 + dj];
          #pragma unroll
          for (int j = 0; j < 8; ++j) y[j] = fmaf(wv, row[j+dj], y[j]);
        }
      }
      #pragma unroll
      for (int j = 0; j < 8; ++j) s_y[ol][pi*8 + j] = fmaxf(y[j], 0.f);
    }
    __syncthreads();

    // --- GEMM accumulate: acc[i][j] += w1t[o][ci*8+i] * y[o][pi*8+j] ---
    #pragma unroll 4
    for (int o = 0; o < 32; ++o) {
      const float4 wa = *(const float4*)&s_w1[o][ci*8];
      const float4 wb = *(const float4*)&s_w1[o][ci*8+4];
      const float4 ya = *(const float4*)&s_y[o][pi*8];
      const float4 yb = *(const float4*)&s_y[o][pi*8+4];
      float wv[8], yv[8];
      wv[0]=wa.x; wv[1]=wa.y; wv[2]=wa.z; wv[3]=wa.w;
      wv[4]=wb.x; wv[5]=wb.y; wv[6]=wb.z; wv[7]=wb.w;
      yv[0]=ya.x; yv[1]=ya.y; yv[2]=ya.z; yv[3]=ya.w;
      yv[4]=yb.x; yv[5]=yb.y; yv[6]=yb.z; yv[7]=yb.w;
      #pragma unroll
      for (int i = 0; i < 8; ++i)
        #pragma unroll
        for (int j = 0; j < 8; ++j)
          acc[i][j] = fmaf(wv[i], yv[j], acc[i][j]);
    }
    __syncthreads();
  }

  // --- epilogue: + b1 + residual x ---
  {
    const int pr  = pi >> 1;
    const int pc0 = (pi & 1) * 8;
    const int h   = h0 + pr;
    #pragma unroll
    for (int i = 0; i < 8; ++i) {
      const int c = ci*8 + i;
      const float bias = b1[c];
      const int base = ((b*C_ + c)*H_ + h)*W_ + w0 + pc0;
      const float4 xa = *(const float4*)&x[base];
      const float4 xb = *(const float4*)&x[base+4];
      float4 oa, ob;
      oa.x = acc[i][0] + bias + xa.x;
      oa.y = acc[i][1] + bias + xa.y;
      oa.z = acc[i][2] + bias + xa.z;
      oa.w = acc[i][3] + bias + xa.w;
      ob.x = acc[i][4] + bias + xb.x;
      ob.y = acc[i][5] + bias + xb.y;
      ob.z = acc[i][6] + bias + xb.z;
      ob.w = acc[i][7] + bias + xb.w;
      *(float4*)&out[base]   = oa;
      *(float4*)&out[base+4] = ob;
    }
  }
}

extern "C" void kernel_launch(void* const* d_in, const int* in_sizes, int n_in,
                              void* d_out, int out_size, void* d_ws, size_t ws_size,
                              hipStream_t stream) {
  const float* x     = (const float*)d_in[0];
  const float* gamma = (const float*)d_in[1];
  const float* beta  = (const float*)d_in[2];
  const float* lbpw  = (const float*)d_in[3];
  const float* w1    = (const float*)d_in[4];
  const float* b1    = (const float*)d_in[5];
  float* out   = (float*)d_out;
  float* sc_sh = (float*)d_ws;   // [0..255] scale, [256..511] shift

  bn_stats<<<dim3(C_), dim3(1024), 0, stream>>>(x, gamma, beta, sc_sh);

  dim3 grid(W_/TW_, H_/TH_, B_);
  fused_main<<<grid, dim3(256), 0, stream>>>(x, lbpw, w1, b1, sc_sh, out);
}

// Round 2
// 446.449 us; speedup vs baseline: 1.5467x; 1.5467x over previous
//
#include <hip/hip_runtime.h>

#define B_ 8
#define C_ 256
#define H_ 128
#define W_ 128
#define NW_ 512
#define HW_ (H_*W_)
#define EPS_ 1e-5f

typedef __attribute__((ext_vector_type(8))) short bf16x8;
typedef __attribute__((ext_vector_type(4))) float f32x4;

// RNE float -> bf16
__device__ __forceinline__ unsigned short f2bf(float f) {
  unsigned u = __float_as_uint(f);
  u += 0x7fffu + ((u >> 16) & 1u);
  return (unsigned short)(u >> 16);
}
__device__ __forceinline__ float bf2f(unsigned short h) {
  return __uint_as_float(((unsigned)h) << 16);
}
__device__ __forceinline__ float bflo(unsigned u) { return __uint_as_float(u << 16); }
__device__ __forceinline__ float bfhi(unsigned u) { return __uint_as_float(u & 0xffff0000u); }

// ---------- BN stats, two-stage ----------
// Stage 1: one block per (b, c) plane (16384 elems) -> partial sum/sumsq
__global__ __launch_bounds__(256)
void bn_partial(const float* __restrict__ x, float* __restrict__ psum,
                float* __restrict__ psq) {
  const int b = blockIdx.x, c = blockIdx.y, tid = threadIdx.x;
  const float4* p = (const float4*)(x + (size_t)(b*C_ + c) * HW_);
  float s = 0.f, s2 = 0.f;
  #pragma unroll
  for (int i = 0; i < 16; ++i) {
    float4 v = p[tid + i*256];
    s  += v.x + v.y + v.z + v.w;
    s2 += v.x*v.x + v.y*v.y + v.z*v.z + v.w*v.w;
  }
  #pragma unroll
  for (int off = 32; off > 0; off >>= 1) {
    s  += __shfl_down(s, off);
    s2 += __shfl_down(s2, off);
  }
  __shared__ float rs[4], rq[4];
  if ((tid & 63) == 0) { rs[tid >> 6] = s; rq[tid >> 6] = s2; }
  __syncthreads();
  if (tid == 0) {
    float S = rs[0]+rs[1]+rs[2]+rs[3], S2 = rq[0]+rq[1]+rq[2]+rq[3];
    psum[c*B_ + b] = S;
    psq [c*B_ + b] = S2;
  }
}

// Stage 2: finalize scale/shift (one block, thread = channel)
__global__ __launch_bounds__(256)
void bn_final(float* __restrict__ wsf, const float* __restrict__ gamma,
              const float* __restrict__ beta) {
  const int c = threadIdx.x;
  float S = 0.f, S2 = 0.f;
  #pragma unroll
  for (int b = 0; b < B_; ++b) { S += wsf[512 + c*B_ + b]; S2 += wsf[2560 + c*B_ + b]; }
  const float n = (float)(B_*HW_);
  float mean = S / n;
  float var  = S2 / n - mean*mean;
  float scl  = gamma[c] * rsqrtf(var + EPS_);
  wsf[c]       = scl;
  wsf[C_ + c]  = beta[c] - mean*scl;
}

// ---------- w1 -> bf16 A-fragment table ----------
// frag[(mtG*16 + ks)*64 + lane][j] = w1[mtG*16 + (lane&15)][ks*32 + (lane>>4)*8 + j]
__global__ __launch_bounds__(64)
void w1prep(const float* __restrict__ w1, ushort* __restrict__ w1f) {
  const int l15 = threadIdx.x & 15, quad = threadIdx.x >> 4;
  const int mtG = blockIdx.x >> 4, ks = blockIdx.x & 15;
  const float* src = w1 + (size_t)(mtG*16 + l15)*NW_ + ks*32 + quad*8;
  float4 f0 = *(const float4*)src, f1 = *(const float4*)(src + 4);
  union { unsigned u[4]; uint4 q; } cv;
  cv.u[0] = (unsigned)f2bf(f0.x) | ((unsigned)f2bf(f0.y) << 16);
  cv.u[1] = (unsigned)f2bf(f0.z) | ((unsigned)f2bf(f0.w) << 16);
  cv.u[2] = (unsigned)f2bf(f1.x) | ((unsigned)f2bf(f1.y) << 16);
  cv.u[3] = (unsigned)f2bf(f1.z) | ((unsigned)f2bf(f1.w) << 16);
  ((uint4*)w1f)[blockIdx.x*64 + threadIdx.x] = cv.q;
}

// ---------- fused: BN-apply + dw3x3 + relu + 1x1 (MFMA) + bias + residual ----------
// grid (W/16, H/4, B), 256 threads (4 waves). Tile: 4x16 = 64 px, all 256 out ch.
// LDS total = 50688 B -> 3 blocks/CU.
template<bool PREW1>
__global__ __launch_bounds__(256, 2)
void fused_mfma(const float* __restrict__ x, const float* __restrict__ lbpw,
                const float* __restrict__ w1raw, const ushort* __restrict__ w1f,
                const float* __restrict__ b1, const float* __restrict__ sc_sh,
                float* __restrict__ out) {
  const int tid  = threadIdx.x;
  const int b    = blockIdx.z;
  const int h0   = blockIdx.y * 4;
  const int w0   = blockIdx.x * 16;
  const int wave = tid >> 6;
  const int lane = tid & 63;
  const int l15  = lane & 15;
  const int quad = lane >> 4;

  __shared__ float  s_scale[C_];
  __shared__ float  s_shift[C_];
  __shared__ float  s_b1[C_];
  __shared__ __align__(16) float  s_xn[16][6][20];   // chunk of 16 in-ch, halo tile (pitch 20)
  __shared__ __align__(16) ushort s_yT[64][40];      // y transposed [px][o_local], pitch 40
  __shared__ __align__(16) ushort s_wc[32][16];      // lbp weights chunk, bf16 (exact)
  __shared__ __align__(16) ushort s_res[256][66];    // raw-x stash bf16, pitch 66 (bank spread)

  s_scale[tid] = sc_sh[tid];
  s_shift[tid] = sc_sh[C_ + tid];
  s_b1[tid]    = b1[tid];

  // dwconv mapping: thread = (cin 0..15, col 0..15); computes o = 2cin,2cin+1 at 4 rows
  const int ccin = tid >> 4;
  const int ccol = tid & 15;

  f32x4 acc[4][4];
  #pragma unroll
  for (int mt = 0; mt < 4; ++mt)
    #pragma unroll
    for (int nt = 0; nt < 4; ++nt) {
      f32x4 z = {0.f, 0.f, 0.f, 0.f};
      acc[mt][nt] = z;
    }

  __syncthreads();

  #pragma unroll 1
  for (int kc = 0; kc < 16; ++kc) {
    const int c0 = kc * 16;   // input-channel base
    const int o0 = kc * 32;   // y-channel base

    // ---- stage normalized tile (zero pad in xn space) + stash raw interior ----
    for (int idx = tid; idx < 16*6*18; idx += 256) {
      const int cl  = idx / 108;
      const int rem = idx - cl * 108;
      const int r   = rem / 18;
      const int col = rem - r * 18;
      const int h = h0 + r - 1;
      const int w = w0 + col - 1;
      float v = 0.f;
      if (h >= 0 && h < H_ && w >= 0 && w < W_) {
        const float xv = x[((size_t)(b*C_ + c0 + cl)*H_ + h)*W_ + w];
        v = fmaf(xv, s_scale[c0 + cl], s_shift[c0 + cl]);
        if (r >= 1 && r <= 4 && col >= 1 && col <= 16)
          s_res[c0 + cl][(r-1)*16 + (col-1)] = f2bf(xv);
      }
      s_xn[cl][r][col] = v;
    }
    // ---- stage weight chunk (exact in bf16: {-1,0,1}) ----
    for (int idx = tid; idx < 32*9; idx += 256) {
      const int oo = idx / 9;
      const int j  = idx - oo * 9;
      s_wc[oo][j] = f2bf(lbpw[(size_t)(o0 + oo)*9 + j]);
    }
    __syncthreads();

    // ---- depthwise 3x3 + relu -> s_yT ----
    {
      float v[6][3];
      #pragma unroll
      for (int rr = 0; rr < 6; ++rr)
        #pragma unroll
        for (int dj = 0; dj < 3; ++dj)
          v[rr][dj] = s_xn[ccin][rr][ccol + dj];

      const uint4 qa = *(const uint4*)&s_wc[2*ccin][0];
      const uint4 qb = *(const uint4*)&s_wc[2*ccin + 1][0];
      const float wA[9] = { bflo(qa.x), bfhi(qa.x), bflo(qa.y), bfhi(qa.y),
                            bflo(qa.z), bfhi(qa.z), bflo(qa.w), bfhi(qa.w),
                            bf2f(s_wc[2*ccin][8]) };
      const float wB[9] = { bflo(qb.x), bfhi(qb.x), bflo(qb.y), bfhi(qb.y),
                            bflo(qb.z), bfhi(qb.z), bflo(qb.w), bfhi(qb.w),
                            bf2f(s_wc[2*ccin + 1][8]) };
      float a0[4] = {0.f,0.f,0.f,0.f}, a1[4] = {0.f,0.f,0.f,0.f};
      #pragma unroll
      for (int r = 0; r < 4; ++r)
        #pragma unroll
        for (int di = 0; di < 3; ++di)
          #pragma unroll
          for (int dj = 0; dj < 3; ++dj) {
            const float t = v[r + di][dj];
            a0[r] = fmaf(wA[di*3 + dj], t, a0[r]);
            a1[r] = fmaf(wB[di*3 + dj], t, a1[r]);
          }
      #pragma unroll
      for (int r = 0; r < 4; ++r) {
        const unsigned pk = (unsigned)f2bf(fmaxf(a0[r], 0.f)) |
                            ((unsigned)f2bf(fmaxf(a1[r], 0.f)) << 16);
        *(unsigned*)&s_yT[r*16 + ccol][2*ccin] = pk;
      }
    }
    __syncthreads();

    // ---- GEMM: acc[ch][px] += w1[ch][o] * y[o][px], K=32 per chunk ----
    bf16x8 bfr[4];
    #pragma unroll
    for (int nt = 0; nt < 4; ++nt)
      bfr[nt] = *(const bf16x8*)&s_yT[nt*16 + l15][quad*8];

    #pragma unroll
    for (int mt = 0; mt < 4; ++mt) {
      bf16x8 afr;
      if constexpr (PREW1) {
        union { uint4 q; bf16x8 v; } cv;
        cv.q = *(const uint4*)(w1f + (size_t)(((wave*4 + mt)*16 + kc)*64 + lane)*8);
        afr = cv.v;
      } else {
        const float* wp = w1raw + (size_t)(wave*64 + mt*16 + l15)*NW_ + o0 + quad*8;
        const float4 f0 = *(const float4*)wp;
        const float4 f1 = *(const float4*)(wp + 4);
        union { unsigned u[4]; bf16x8 v; } cv;
        cv.u[0] = (unsigned)f2bf(f0.x) | ((unsigned)f2bf(f0.y) << 16);
        cv.u[1] = (unsigned)f2bf(f0.z) | ((unsigned)f2bf(f0.w) << 16);
        cv.u[2] = (unsigned)f2bf(f1.x) | ((unsigned)f2bf(f1.y) << 16);
        cv.u[3] = (unsigned)f2bf(f1.z) | ((unsigned)f2bf(f1.w) << 16);
        afr = cv.v;
      }
      #pragma unroll
      for (int nt = 0; nt < 4; ++nt)
        acc[mt][nt] = __builtin_amdgcn_mfma_f32_16x16x32_bf16(afr, bfr[nt], acc[mt][nt], 0, 0, 0);
    }
    __syncthreads();
  }

  // ---- epilogue: + b1 + raw-x residual (from LDS stash) ----
  #pragma unroll
  for (int mt = 0; mt < 4; ++mt) {
    #pragma unroll
    for (int nt = 0; nt < 4; ++nt) {
      const int h   = h0 + nt;
      const int wcl = w0 + l15;
      const int px  = nt*16 + l15;
      #pragma unroll
      for (int i = 0; i < 4; ++i) {
        const int ch = wave*64 + mt*16 + quad*4 + i;
        const float r = bf2f(s_res[ch][px]);
        out[((size_t)(b*C_ + ch)*H_ + h)*W_ + wcl] = acc[mt][nt][i] + s_b1[ch] + r;
      }
    }
  }
}

extern "C" void kernel_launch(void* const* d_in, const int* in_sizes, int n_in,
                              void* d_out, int out_size, void* d_ws, size_t ws_size,
                              hipStream_t stream) {
  const float* x     = (const float*)d_in[0];
  const float* gamma = (const float*)d_in[1];
  const float* beta  = (const float*)d_in[2];
  const float* lbpw  = (const float*)d_in[3];
  const float* w1    = (const float*)d_in[4];
  const float* b1    = (const float*)d_in[5];
  float* out = (float*)d_out;

  // ws layout (floats): [0,256) scale | [256,512) shift | [512,2560) psum |
  //                     [2560,4608) psq | byte 18432: w1 bf16 frag table (256 KB)
  float* wsf = (float*)d_ws;
  ushort* w1f = (ushort*)((char*)d_ws + 18432);
  const bool pre = ws_size >= (size_t)(18432 + 262144);

  bn_partial<<<dim3(B_, C_), 256, 0, stream>>>(x, wsf + 512, wsf + 2560);
  bn_final<<<1, 256, 0, stream>>>(wsf, gamma, beta);

  dim3 grid(W_/16, H_/4, B_);
  if (pre) {
    w1prep<<<256, 64, 0, stream>>>(w1, w1f);
    fused_mfma<true><<<grid, 256, 0, stream>>>(x, lbpw, w1, w1f, b1, wsf, out);
  } else {
    fused_mfma<false><<<grid, 256, 0, stream>>>(x, lbpw, w1, w1f, b1, wsf, out);
  }
}